// Round 13
// baseline (46.035 us; speedup 1.0000x reference)
//
#include <hip/hip_runtime.h>

// PGA G(3,0,1) geometric product, pairwise: out[n,m,:] = T[n] * reverse(T[m]).
// R7: R6 with NB=4 (each thread computes 4 consecutive n for its m). b loaded
// once per thread (b-load traffic amortized 4x), a via wave-uniform scalar
// loads per iteration, LDS store-transpose region reused sequentially
// (same-wave in-order DS -> zero barriers), grid = nrows/256 x nrows/4.

namespace {

typedef float f4 __attribute__((ext_vector_type(4)));

constexpr int popcount4(unsigned x) {
    int c = 0;
    for (int i = 0; i < 5; ++i) c += (x >> i) & 1;
    return c;
}

struct GPTab {
    signed char sgn[16][16];   // sign of e_j * e_k (rev on k folded in); 0 if vanishes
    unsigned char idx[16][16]; // output blade index of e_j * e_k
};

// Blade bitmasks in the reference's basis order:
// (), e0..e3, e01,e02,e03,e12,e13,e23, e012,e013,e023,e123, e0123
constexpr unsigned MASKV[16] = {0u, 1u, 2u, 4u, 8u,
                                3u, 5u, 9u, 6u, 10u, 12u,
                                7u, 11u, 13u, 14u, 15u};

constexpr GPTab make_tab() {
    GPTab t{};
    int inv[16] = {};
    for (int i = 0; i < 16; ++i) inv[(int)MASKV[i]] = i;

    for (int j = 0; j < 16; ++j) {
        for (int k = 0; k < 16; ++k) {
            unsigned a = MASKV[j], b = MASKV[k];
            if (a & b & 1u) {            // shared e0 -> e0^2 = 0
                t.sgn[j][k] = 0;
                t.idx[j][k] = 0;
                continue;
            }
            int swaps = 0;
            for (int g = 0; g < 4; ++g)
                if ((b >> g) & 1u)
                    swaps += popcount4(a >> (g + 1));
            int s = (swaps & 1) ? -1 : 1;
            int r = popcount4(b);
            if ((r * (r - 1) / 2) & 1) s = -s;   // reverse() on 2nd operand
            t.sgn[j][k] = (signed char)s;
            t.idx[j][k] = (unsigned char)inv[(int)(a ^ b)];
        }
    }
    return t;
}

constexpr GPTab TAB = make_tab();

} // namespace

// Requires nrows % 256 == 0 and nrows % 4 == 0 (harness: nrows = 2048).
__global__ __launch_bounds__(256) void gp_fused_kernel(
    const float* __restrict__ T, float* __restrict__ out, int nrows) {
    const int lane = threadIdx.x & 63;
    const int wave = threadIdx.x >> 6;
    const int t    = threadIdx.x;
    const int m0   = blockIdx.x * 256;
    const int n0   = blockIdx.y * 4;          // wave-uniform; four n per thread

    // Per-wave 64-pair store-transpose region, padded stride 20 floats. 20 KB.
    __shared__ float lds[256 * 20];

    // ---- b: this thread's own pair, direct strided f4 loads (L2-resident) ----
    float b[16];
    {
        const f4* __restrict__ Tb = reinterpret_cast<const f4*>(T) + (size_t)(m0 + t) * 4;
#pragma unroll
        for (int q = 0; q < 4; ++q) {
            f4 v = Tb[q];
            b[q * 4 + 0] = v.x; b[q * 4 + 1] = v.y;
            b[q * 4 + 2] = v.z; b[q * 4 + 3] = v.w;
        }
    }

    const int waveM0 = m0 + wave * 64;
    const float* wbase = &lds[wave * 64 * 20];
    float* w = &lds[t * 20];

#pragma unroll
    for (int nn = 0; nn < 4; ++nn) {
        const int n = n0 + nn;

        // ---- a: wave-uniform -> scalar loads (SGPRs) ----
        float a[16];
        {
            const float* __restrict__ An = T + (size_t)n * 16;
#pragma unroll
            for (int j = 0; j < 16; ++j) a[j] = An[j];
        }

        // ---- geometric product: 192 scalar FMAs, table-driven ----
        float o[16];
#pragma unroll
        for (int i = 0; i < 16; ++i) o[i] = 0.0f;

#pragma unroll
        for (int j = 0; j < 16; ++j) {
#pragma unroll
            for (int k = 0; k < 16; ++k) {
                const int s = TAB.sgn[j][k];  // compile-time after unroll
                const int i = TAB.idx[j][k];
                if (s == 1) {
                    o[i] = fmaf(a[j], b[k], o[i]);
                } else if (s == -1) {
                    o[i] = fmaf(-a[j], b[k], o[i]);
                }
            }
        }

        // ---- same-wave LDS store-transpose (no barrier; region reused across
        //      nn — per-wave in-order DS makes write-after-read safe) ----
#pragma unroll
        for (int q = 0; q < 4; ++q) {
            f4 v; v.x = o[q * 4 + 0]; v.y = o[q * 4 + 1];
            v.z = o[q * 4 + 2]; v.w = o[q * 4 + 3];
            *reinterpret_cast<f4*>(w + q * 4) = v;
        }

        f4* __restrict__ ov =
            reinterpret_cast<f4*>(out) + ((size_t)n * nrows + waveM0) * 4;
#pragma unroll
        for (int q = 0; q < 4; ++q) {
            const int g = q * 64 + lane;      // float4 index within wave tile
            const int p = g >> 2;
            const int c = g & 3;
            f4 v = *reinterpret_cast<const f4*>(&wbase[p * 20 + c * 4]);
            ov[g] = v;                        // coalesced 1 KB/instr
        }
    }
}

extern "C" void kernel_launch(void* const* d_in, const int* in_sizes, int n_in,
                              void* d_out, int out_size, void* d_ws, size_t ws_size,
                              hipStream_t stream) {
    const float* T = (const float*)d_in[0];
    float* out = (float*)d_out;
    const int nrows = in_sizes[0] / 16;       // 2048 (multiple of 256 and of 4)
    dim3 grid((unsigned)(nrows / 256), (unsigned)(nrows / 4), 1);
    gp_fused_kernel<<<grid, 256, 0, stream>>>(T, out, nrows);
}

// Round 14
// 45.236 us; speedup vs baseline: 1.0177x; 1.0177x over previous
//
#include <hip/hip_runtime.h>

// PGA G(3,0,1) geometric product, pairwise: out[n,m,:] = T[n] * reverse(T[m]).
// R8 = R6 revert (measured optimum, 45.25 us): NB=2 n-blocking. b loaded once
// per thread (strided f4, L2-resident), a via wave-uniform scalar loads, LDS
// store-transpose region reused sequentially (same-wave in-order DS -> zero
// barriers), plain dwordx4 stores (NT costs +12us on gfx950). NB=4 regressed
// (46.0) — longer serial store chain per thread; NB=2 is the sweet spot.

namespace {

typedef float f4 __attribute__((ext_vector_type(4)));

constexpr int popcount4(unsigned x) {
    int c = 0;
    for (int i = 0; i < 5; ++i) c += (x >> i) & 1;
    return c;
}

struct GPTab {
    signed char sgn[16][16];   // sign of e_j * e_k (rev on k folded in); 0 if vanishes
    unsigned char idx[16][16]; // output blade index of e_j * e_k
};

// Blade bitmasks in the reference's basis order:
// (), e0..e3, e01,e02,e03,e12,e13,e23, e012,e013,e023,e123, e0123
constexpr unsigned MASKV[16] = {0u, 1u, 2u, 4u, 8u,
                                3u, 5u, 9u, 6u, 10u, 12u,
                                7u, 11u, 13u, 14u, 15u};

constexpr GPTab make_tab() {
    GPTab t{};
    int inv[16] = {};
    for (int i = 0; i < 16; ++i) inv[(int)MASKV[i]] = i;

    for (int j = 0; j < 16; ++j) {
        for (int k = 0; k < 16; ++k) {
            unsigned a = MASKV[j], b = MASKV[k];
            if (a & b & 1u) {            // shared e0 -> e0^2 = 0
                t.sgn[j][k] = 0;
                t.idx[j][k] = 0;
                continue;
            }
            int swaps = 0;
            for (int g = 0; g < 4; ++g)
                if ((b >> g) & 1u)
                    swaps += popcount4(a >> (g + 1));
            int s = (swaps & 1) ? -1 : 1;
            int r = popcount4(b);
            if ((r * (r - 1) / 2) & 1) s = -s;   // reverse() on 2nd operand
            t.sgn[j][k] = (signed char)s;
            t.idx[j][k] = (unsigned char)inv[(int)(a ^ b)];
        }
    }
    return t;
}

constexpr GPTab TAB = make_tab();

} // namespace

// Requires nrows % 256 == 0 and nrows even (harness: nrows = 2048).
__global__ __launch_bounds__(256) void gp_fused_kernel(
    const float* __restrict__ T, float* __restrict__ out, int nrows) {
    const int lane = threadIdx.x & 63;
    const int wave = threadIdx.x >> 6;
    const int t    = threadIdx.x;
    const int m0   = blockIdx.x * 256;
    const int n0   = blockIdx.y * 2;          // wave-uniform; two n per thread

    // Per-wave 64-pair store-transpose region, padded stride 20 floats. 20 KB.
    __shared__ float lds[256 * 20];

    // ---- b: this thread's own pair, direct strided f4 loads (L2-resident) ----
    float b[16];
    {
        const f4* __restrict__ Tb = reinterpret_cast<const f4*>(T) + (size_t)(m0 + t) * 4;
#pragma unroll
        for (int q = 0; q < 4; ++q) {
            f4 v = Tb[q];
            b[q * 4 + 0] = v.x; b[q * 4 + 1] = v.y;
            b[q * 4 + 2] = v.z; b[q * 4 + 3] = v.w;
        }
    }

    const int waveM0 = m0 + wave * 64;
    const float* wbase = &lds[wave * 64 * 20];
    float* w = &lds[t * 20];

#pragma unroll
    for (int nn = 0; nn < 2; ++nn) {
        const int n = n0 + nn;

        // ---- a: wave-uniform -> scalar loads (SGPRs) ----
        float a[16];
        {
            const float* __restrict__ An = T + (size_t)n * 16;
#pragma unroll
            for (int j = 0; j < 16; ++j) a[j] = An[j];
        }

        // ---- geometric product: 192 scalar FMAs, table-driven ----
        float o[16];
#pragma unroll
        for (int i = 0; i < 16; ++i) o[i] = 0.0f;

#pragma unroll
        for (int j = 0; j < 16; ++j) {
#pragma unroll
            for (int k = 0; k < 16; ++k) {
                const int s = TAB.sgn[j][k];  // compile-time after unroll
                const int i = TAB.idx[j][k];
                if (s == 1) {
                    o[i] = fmaf(a[j], b[k], o[i]);
                } else if (s == -1) {
                    o[i] = fmaf(-a[j], b[k], o[i]);
                }
            }
        }

        // ---- same-wave LDS store-transpose (no barrier; region reused across
        //      nn — per-wave in-order DS makes write-after-read safe) ----
#pragma unroll
        for (int q = 0; q < 4; ++q) {
            f4 v; v.x = o[q * 4 + 0]; v.y = o[q * 4 + 1];
            v.z = o[q * 4 + 2]; v.w = o[q * 4 + 3];
            *reinterpret_cast<f4*>(w + q * 4) = v;
        }

        f4* __restrict__ ov =
            reinterpret_cast<f4*>(out) + ((size_t)n * nrows + waveM0) * 4;
#pragma unroll
        for (int q = 0; q < 4; ++q) {
            const int g = q * 64 + lane;      // float4 index within wave tile
            const int p = g >> 2;
            const int c = g & 3;
            f4 v = *reinterpret_cast<const f4*>(&wbase[p * 20 + c * 4]);
            ov[g] = v;                        // coalesced 1 KB/instr
        }
    }
}

extern "C" void kernel_launch(void* const* d_in, const int* in_sizes, int n_in,
                              void* d_out, int out_size, void* d_ws, size_t ws_size,
                              hipStream_t stream) {
    const float* T = (const float*)d_in[0];
    float* out = (float*)d_out;
    const int nrows = in_sizes[0] / 16;       // 2048 (multiple of 256, even)
    dim3 grid((unsigned)(nrows / 256), (unsigned)(nrows / 2), 1);
    gp_fused_kernel<<<grid, 256, 0, stream>>>(T, out, nrows);
}